// Round 9
// baseline (523.717 us; speedup 1.0000x reference)
//
#include <hip/hip_runtime.h>
#include <hip/hip_bf16.h>

// AutoregressiveRoutingHead: B=65536, L=8, LATENT=256, HID=128, NTOK=5
//  K1: G[tok][j] = emb[tok]@W_ih[j] + b_ih[j] + (j<512 ? b_hh[j] : 0)  (6x768 f32)
//  K2: augmented W -> bf16 frag-linear Wg for mfma_f32_16x16x32_bf16.
//      Per wave-slice w (cols 16w..16w+15), 28 frags of 16x32:
//        f = g*8+kc (g<3, kc<8): W_hh[g*256+col][kc*32..+32]
//        f = 24+g: one-hot K-block (k<6 hot): g0/g1 = Gtab r/z cols,
//                  g2 = bhn (any tok), g3 = Gtab i_n cols
//  K3: 1024 blocks x 1024 threads (16 waves -> 4 waves/SIMD, 128-reg cap).
//      Wave w owns gate-cols [16w,16w+16) for r,z,n,i_n across ALL 4 N-tiles
//      (64 batch rows) -> acc[4][4] f32x4 = 64 regs; each A-frag loaded by
//      exactly one wave (L2-stream-optimal). MFMA over K=288 yields
//      bias-complete gates; combine = pure VALU (hold in regs, no LDS read).
//      r9: zero-peeled accumulators (C=z4 const, no 64 v_movs/step),
//      hprev in regs, s_setprio(1) around the MFMA stream phase.
//      h bf16 in LDS, double-buffered, ONE lds_barrier per step. Logits via
//      MFMA on waves 0/5/10/15 (one per SIMD), skewed one step.

typedef __attribute__((ext_vector_type(8)))  __bf16 bf16x8;
typedef __attribute__((ext_vector_type(4)))  __bf16 bf16x4;
typedef __attribute__((ext_vector_type(4)))  float  f32x4;

__device__ __forceinline__ float sigm(float x) {
    return __builtin_amdgcn_rcpf(1.f + __expf(-x));
}
__device__ __forceinline__ float tanh_fast(float x) {
    // tanh(x) = 2*sigmoid(2x) - 1
    return __builtin_fmaf(2.f, __builtin_amdgcn_rcpf(1.f + __expf(-2.f * x)), -1.f);
}
__device__ __forceinline__ void lds_barrier() {
    // LDS-only barrier: drains ds ops, NOT vmem.
    __builtin_amdgcn_sched_barrier(0);
    asm volatile("s_waitcnt lgkmcnt(0)" ::: "memory");
    __builtin_amdgcn_s_barrier();
    __builtin_amdgcn_sched_barrier(0);
}

// ---------------- K1: gi table ----------------
__global__ void k_gtable(const float* __restrict__ emb, const float* __restrict__ W_ih,
                         const float* __restrict__ b_ih, const float* __restrict__ b_hh,
                         float* __restrict__ G) {
    int tok = blockIdx.x;      // 0..5
    int j   = threadIdx.x;     // 0..767
    const float4* e4 = (const float4*)(emb + tok * 128);
    const float4* w4 = (const float4*)(W_ih + (size_t)j * 128);
    float s = 0.f;
#pragma unroll
    for (int k = 0; k < 32; ++k) {
        float4 a = e4[k], b = w4[k];
        s += a.x * b.x + a.y * b.y + a.z * b.z + a.w * b.w;
    }
    s += b_ih[j];
    if (j < 512) s += b_hh[j];   // fold b_hh into r,z gate pre-activations
    G[tok * 768 + j] = s;
}

// ---------------- K2: augmented W -> 16x16x32 A-frags ----------------
// Frag layout: lane = m + 16*kq (m=0..15, kq=0..3), elem j -> k = kq*8+j.
__global__ void k_wfrag3(const float* __restrict__ Whh, const float* __restrict__ Gtab,
                         const float* __restrict__ b_hh, __bf16* __restrict__ Wg) {
    int u    = blockIdx.x * 256 + threadIdx.x;   // 0..28671 (448 frags x 64 lanes)
    int lane = u & 63;
    int frag = u >> 6;            // 0..447
    int w    = frag / 28;
    int f    = frag - 28 * w;     // 0..27
    int col  = w * 16 + (lane & 15);
    int kq   = lane >> 4;
    bf16x8 v;
    if (f < 24) {
        int g = f >> 3, kc = f & 7;
        const float* src = Whh + (size_t)(g * 256 + col) * 256 + kc * 32 + kq * 8;
#pragma unroll
        for (int j = 0; j < 8; ++j) v[j] = (__bf16)src[j];
    } else {
        int g = f - 24;
#pragma unroll
        for (int j = 0; j < 8; ++j) {
            int k = kq * 8 + j;
            float val = 0.f;
            if (k < 6) {
                val = (g == 0) ? Gtab[k * 768 + col]
                    : (g == 1) ? Gtab[k * 768 + 256 + col]
                    : (g == 2) ? b_hh[512 + col]
                               : Gtab[k * 768 + 512 + col];
            }
            v[j] = (__bf16)val;
        }
    }
    *(bf16x8*)(Wg + (size_t)u * 8) = v;
}

// ---------------- K3: main recurrent kernel ----------------
__global__ __launch_bounds__(1024) void k_main(
    const float* __restrict__ latent, const int* __restrict__ tgt,
    const __bf16* __restrict__ Wg, const float* __restrict__ Wout,
    const float* __restrict__ bout, float* __restrict__ out) {

    __shared__ __bf16 h_lds[2][4][8][64][8];    // [buf][nt][kc][lane][j] : 64 KB
    __shared__ __bf16 onehot_lds[8][4][64][8];  // per-step one-hot B-frags : 32 KB
    __shared__ __bf16 woutf_lds[8][64][8];      // W_out A-frags (rows 5..15 = 0) : 8 KB
    __shared__ float  logit_lds[64 * 40];       // logits (10 KB)

    const int tid  = threadIdx.x;
    const int lane = tid & 63;
    const int w    = tid >> 6;       // wave 0..15 : gate-col slice [16w,16w+16)
    const int q    = lane >> 4;      // k-quad within frag / row-quad in C
    const int n16  = lane & 15;      // batch index within 16-row N-tile
    const int row0 = blockIdx.x * 64;

    // per-thread A-frag base; local frag f at wbase + f*512 elements
    const __bf16* wbase = Wg + ((size_t)(w * 28) * 64 + lane) * 8;

    // combine-element <-> B-frag LDS mapping:
    // element (nt, col=16w+4q+i): kc_h=w>>1, lane'=n16+16*((2w+(q>>1))&3), j=4*(q&1)+i
    const int kc_h  = w >> 1;
    const int slotl = n16 + 16 * ((2 * w + (q >> 1)) & 3);
    const int joff  = 4 * (q & 1);

    // ---- stage W_out A-frags (16 rows, 5 used) ----
    if (tid < 512) {
        int kc = tid >> 6, ln = tid & 63, m = ln & 15, kq2 = ln >> 4;
        bf16x8 v;
#pragma unroll
        for (int j = 0; j < 8; ++j)
            v[j] = (m < 5) ? (__bf16)Wout[m * 256 + kc * 32 + kq2 * 8 + j] : (__bf16)0.f;
        *(bf16x8*)&woutf_lds[kc][ln][0] = v;
    }
    // ---- one-hot B-frags for all 8 steps ----
    for (int s = tid; s < 2048; s += 1024) {
        int t = s >> 8, nt = (s >> 6) & 3, ln = s & 63;
        int nn = ln & 15, kq2 = ln >> 4;
        int tok = (t == 0) ? 5 : tgt[(size_t)(row0 + nt * 16 + nn) * 8 + t - 1];
        bf16x8 v;
#pragma unroll
        for (int j = 0; j < 8; ++j) v[j] = (__bf16)((kq2 * 8 + j == tok) ? 1.f : 0.f);
        *(bf16x8*)&onehot_lds[t][nt][ln][0] = v;
    }
    // ---- init h in LDS buf 0 (bf16) + hprev in regs ----
    bf16x4 hprev[4];
#pragma unroll
    for (int nt = 0; nt < 4; ++nt) {
        float4 hv = *(const float4*)(latent + (size_t)(row0 + nt * 16 + n16) * 256 + 16 * w + 4 * q);
        bf16x4 hb;
        hb[0] = (__bf16)hv.x; hb[1] = (__bf16)hv.y;
        hb[2] = (__bf16)hv.z; hb[3] = (__bf16)hv.w;
        hprev[nt] = hb;
        *(bf16x4*)&h_lds[0][nt][kc_h][slotl][joff] = hb;
    }
    // logit-wave assignment: one per SIMD (waves 0,5,10,15 -> nt 0..3)
    const int lw = (w == 0) ? 0 : (w == 5) ? 1 : (w == 10) ? 2 : (w == 15) ? 3 : -1;
    const float bo0 = bout[0], bo1 = bout[1], bo2 = bout[2], bo3 = bout[3], bo4 = bout[4];
    const f32x4 z4 = {0.f, 0.f, 0.f, 0.f};
    __syncthreads();

    for (int t = 0; t < 8; ++t) {
        const int cur = t & 1, nxt = cur ^ 1;
        f32x4 acc[4][4];   // [gate][nt]; no explicit zero-init (peeled C=z4)

        __builtin_amdgcn_s_setprio(1);
        // ---- peeled kc=0: C = z4 (kills 64 acc-init movs per step) ----
        {
            bf16x8 a0 = *(const bf16x8*)(wbase);
            bf16x8 a1 = *(const bf16x8*)(wbase + (size_t)8 * 512);
            bf16x8 a2 = *(const bf16x8*)(wbase + (size_t)16 * 512);
#pragma unroll
            for (int nt = 0; nt < 4; ++nt) {
                bf16x8 bb = *(const bf16x8*)&h_lds[cur][nt][0][lane][0];
                acc[0][nt] = __builtin_amdgcn_mfma_f32_16x16x32_bf16(a0, bb, z4, 0, 0, 0);
                acc[1][nt] = __builtin_amdgcn_mfma_f32_16x16x32_bf16(a1, bb, z4, 0, 0, 0);
                acc[2][nt] = __builtin_amdgcn_mfma_f32_16x16x32_bf16(a2, bb, z4, 0, 0, 0);
            }
        }
        // ---- stream kc 1..7 from L2 ----
#pragma unroll 2
        for (int kc = 1; kc < 8; ++kc) {
            bf16x8 a0 = *(const bf16x8*)(wbase + (size_t)kc * 512);
            bf16x8 a1 = *(const bf16x8*)(wbase + (size_t)(8 + kc) * 512);
            bf16x8 a2 = *(const bf16x8*)(wbase + (size_t)(16 + kc) * 512);
#pragma unroll
            for (int nt = 0; nt < 4; ++nt) {
                bf16x8 bb = *(const bf16x8*)&h_lds[cur][nt][kc][lane][0];
                acc[0][nt] = __builtin_amdgcn_mfma_f32_16x16x32_bf16(a0, bb, acc[0][nt], 0, 0, 0);
                acc[1][nt] = __builtin_amdgcn_mfma_f32_16x16x32_bf16(a1, bb, acc[1][nt], 0, 0, 0);
                acc[2][nt] = __builtin_amdgcn_mfma_f32_16x16x32_bf16(a2, bb, acc[2][nt], 0, 0, 0);
            }
        }
        // ---- one-hot K-block (i_r,i_z,bhn into acc0..2; i_n inits acc3) ----
        {
            bf16x8 a0 = *(const bf16x8*)(wbase + (size_t)24 * 512);
            bf16x8 a1 = *(const bf16x8*)(wbase + (size_t)25 * 512);
            bf16x8 a2 = *(const bf16x8*)(wbase + (size_t)26 * 512);
            bf16x8 a3 = *(const bf16x8*)(wbase + (size_t)27 * 512);
#pragma unroll
            for (int nt = 0; nt < 4; ++nt) {
                bf16x8 oh = *(const bf16x8*)&onehot_lds[t][nt][lane][0];
                acc[0][nt] = __builtin_amdgcn_mfma_f32_16x16x32_bf16(a0, oh, acc[0][nt], 0, 0, 0);
                acc[1][nt] = __builtin_amdgcn_mfma_f32_16x16x32_bf16(a1, oh, acc[1][nt], 0, 0, 0);
                acc[2][nt] = __builtin_amdgcn_mfma_f32_16x16x32_bf16(a2, oh, acc[2][nt], 0, 0, 0);
                acc[3][nt] = __builtin_amdgcn_mfma_f32_16x16x32_bf16(a3, oh, z4, 0, 0, 0);
            }
        }

        // ---- logit MFMA (skewed one step), one wave per SIMD ----
        if (lw >= 0 && t > 0) {
            f32x4 lacc = z4;
#pragma unroll
            for (int kc = 0; kc < 8; ++kc) {
                bf16x8 wf = *(const bf16x8*)&woutf_lds[kc][lane][0];
                bf16x8 bb = *(const bf16x8*)&h_lds[cur][lw][kc][lane][0];
                lacc = __builtin_amdgcn_mfma_f32_16x16x32_bf16(wf, bb, lacc, 0, 0, 0);
            }
            // C: batch = lane&15, o = q*4 + i
            float* dst = &logit_lds[(lw * 16 + n16) * 40 + (t - 1) * 5];
            if (q == 0) {
                dst[0] = lacc[0] + bo0; dst[1] = lacc[1] + bo1;
                dst[2] = lacc[2] + bo2; dst[3] = lacc[3] + bo3;
            } else if (q == 1) {
                dst[4] = lacc[0] + bo4;
            }
        }
        __builtin_amdgcn_s_setprio(0);

        // ---- combine: pure-VALU GRU update (hold from regs) ----
#pragma unroll
        for (int nt = 0; nt < 4; ++nt) {
            bf16x4 hold = hprev[nt];
            bf16x4 hb;
#pragma unroll
            for (int i = 0; i < 4; ++i) {
                float rg = sigm(acc[0][nt][i]);
                float zg = sigm(acc[1][nt][i]);
                float ng = tanh_fast(__builtin_fmaf(rg, acc[2][nt][i], acc[3][nt][i]));
                float hv = ng + zg * ((float)hold[i] - ng);
                hb[i] = (__bf16)hv;
            }
            hprev[nt] = hb;
            *(bf16x4*)&h_lds[nxt][nt][kc_h][slotl][joff] = hb;
        }
        lds_barrier();   // h_lds[nxt] published; one barrier per step
    }

    // ---- epilogue: logits for step 7 from final h (buf 0 after t=7) ----
    if (lw >= 0) {
        f32x4 lacc = z4;
#pragma unroll
        for (int kc = 0; kc < 8; ++kc) {
            bf16x8 wf = *(const bf16x8*)&woutf_lds[kc][lane][0];
            bf16x8 bb = *(const bf16x8*)&h_lds[0][lw][kc][lane][0];
            lacc = __builtin_amdgcn_mfma_f32_16x16x32_bf16(wf, bb, lacc, 0, 0, 0);
        }
        float* dst = &logit_lds[(lw * 16 + n16) * 40 + 7 * 5];
        if (q == 0) {
            dst[0] = lacc[0] + bo0; dst[1] = lacc[1] + bo1;
            dst[2] = lacc[2] + bo2; dst[3] = lacc[3] + bo3;
        } else if (q == 1) {
            dst[4] = lacc[0] + bo4;
        }
    }
    __syncthreads();
    // ---- coalesced output dump: 64 rows x (8 t x 5 o) contiguous ----
    for (int i = tid; i < 64 * 40; i += 1024)
        out[(size_t)row0 * 40 + i] = logit_lds[i];
}

extern "C" void kernel_launch(void* const* d_in, const int* in_sizes, int n_in,
                              void* d_out, int out_size, void* d_ws, size_t ws_size,
                              hipStream_t stream) {
    const float* latent = (const float*)d_in[0];
    const int*   tgt    = (const int*)d_in[1];
    const float* emb    = (const float*)d_in[2];
    const float* W_ih   = (const float*)d_in[3];
    const float* W_hh   = (const float*)d_in[4];
    const float* b_ih   = (const float*)d_in[5];
    const float* b_hh   = (const float*)d_in[6];
    const float* W_out  = (const float*)d_in[7];
    const float* b_out  = (const float*)d_in[8];
    float* out = (float*)d_out;

    float*  Gtab = (float*)d_ws;                       // 6*768*4 = 18432 B
    __bf16* Wg   = (__bf16*)((char*)d_ws + 18432);     // 448 frags*512*2 = 458752 B

    k_gtable<<<6, 768, 0, stream>>>(emb, W_ih, b_ih, b_hh, Gtab);
    k_wfrag3<<<112, 256, 0, stream>>>(W_hh, Gtab, b_hh, Wg);
    k_main<<<1024, 1024, 0, stream>>>(latent, tgt, Wg, W_out, b_out, out);
}

// Round 10
// 246.064 us; speedup vs baseline: 2.1284x; 2.1284x over previous
//
#include <hip/hip_runtime.h>
#include <hip/hip_bf16.h>

// AutoregressiveRoutingHead: B=65536, L=8, LATENT=256, HID=128, NTOK=5
//  K1: G[tok][j] = (emb[tok]@W_ih[j] + b_ih[j] + (j<512 ? b_hh[j] : 0)) * scale
//      scale = log2e for r,z rows (j<512); 2*log2e for i_n rows (j>=512).
//  K2: augmented W -> bf16 frag-linear Wg for mfma_f32_16x16x32_bf16, with the
//      same exp2 pre-scaling folded in (r,z rows x log2e; n rows x 2log2e).
//      Per wave-slice w (cols 16w..16w+15), 28 frags of 16x32:
//        f = g*8+kc (g<3, kc<8): W_hh[g*256+col][kc*32..+32] * scale_g
//        f = 24+g: one-hot K-block (k<6 hot): g0/g1 = Gtab r/z cols,
//                  g2 = bhn*2log2e, g3 = Gtab i_n cols
//  K3: 1024 blocks x 1024 threads (16 waves -> 4 waves/SIMD, 128-reg cap).
//      Wave w owns gate-cols [16w,16w+16) across all 4 N-tiles; acc[4][4]
//      f32x4 = 64 regs. r10: one-hot K-block runs FIRST with C=z4 (no acc
//      init movs); gates come out bias-complete and exp2-pre-scaled, so
//      combine = rcp/exp2 only (no muls); s_setprio(1) on the MFMA phase.
//      h bf16 in LDS dbuf, hold read from LDS (register-neutral vs r8).
//      ONE lds_barrier/step. Logits via MFMA on waves 0/5/10/15, skewed.

typedef __attribute__((ext_vector_type(8)))  __bf16 bf16x8;
typedef __attribute__((ext_vector_type(4)))  __bf16 bf16x4;
typedef __attribute__((ext_vector_type(4)))  float  f32x4;

#define LOG2E_F     1.4426950408889634f
#define TWO_LOG2E_F 2.8853900817779268f

#if __has_builtin(__builtin_amdgcn_exp2f)
#define EXP2F(x) __builtin_amdgcn_exp2f(x)
#else
#define EXP2F(x) __expf((x) * 0.6931471805599453f)
#endif

// pre-scaled gates: a already multiplied by log2e (sigm) / 2log2e (tanh path)
__device__ __forceinline__ float sigm2(float a) {   // sigmoid(a/log2e)
    return __builtin_amdgcn_rcpf(1.f + EXP2F(-a));
}
__device__ __forceinline__ float tanh2(float a) {   // tanh(a/(2log2e))
    return __builtin_fmaf(2.f, __builtin_amdgcn_rcpf(1.f + EXP2F(-a)), -1.f);
}
__device__ __forceinline__ void lds_barrier() {
    // LDS-only barrier: drains ds ops, NOT vmem.
    __builtin_amdgcn_sched_barrier(0);
    asm volatile("s_waitcnt lgkmcnt(0)" ::: "memory");
    __builtin_amdgcn_s_barrier();
    __builtin_amdgcn_sched_barrier(0);
}

// ---------------- K1: gi table (exp2-pre-scaled) ----------------
__global__ void k_gtable(const float* __restrict__ emb, const float* __restrict__ W_ih,
                         const float* __restrict__ b_ih, const float* __restrict__ b_hh,
                         float* __restrict__ G) {
    int tok = blockIdx.x;      // 0..5
    int j   = threadIdx.x;     // 0..767
    const float4* e4 = (const float4*)(emb + tok * 128);
    const float4* w4 = (const float4*)(W_ih + (size_t)j * 128);
    float s = 0.f;
#pragma unroll
    for (int k = 0; k < 32; ++k) {
        float4 a = e4[k], b = w4[k];
        s += a.x * b.x + a.y * b.y + a.z * b.z + a.w * b.w;
    }
    s += b_ih[j];
    if (j < 512) s = (s + b_hh[j]) * LOG2E_F;   // r,z rows
    else         s = s * TWO_LOG2E_F;           // i_n rows
    G[tok * 768 + j] = s;
}

// ---------------- K2: augmented W -> 16x16x32 A-frags (pre-scaled) --------
// Frag layout: lane = m + 16*kq (m=0..15, kq=0..3), elem j -> k = kq*8+j.
__global__ void k_wfrag3(const float* __restrict__ Whh, const float* __restrict__ Gtab,
                         const float* __restrict__ b_hh, __bf16* __restrict__ Wg) {
    int u    = blockIdx.x * 256 + threadIdx.x;   // 0..28671 (448 frags x 64 lanes)
    int lane = u & 63;
    int frag = u >> 6;            // 0..447
    int w    = frag / 28;
    int f    = frag - 28 * w;     // 0..27
    int col  = w * 16 + (lane & 15);
    int kq   = lane >> 4;
    bf16x8 v;
    if (f < 24) {
        int g = f >> 3, kc = f & 7;
        float scale = (g < 2) ? LOG2E_F : TWO_LOG2E_F;
        const float* src = Whh + (size_t)(g * 256 + col) * 256 + kc * 32 + kq * 8;
#pragma unroll
        for (int j = 0; j < 8; ++j) v[j] = (__bf16)(src[j] * scale);
    } else {
        int g = f - 24;
#pragma unroll
        for (int j = 0; j < 8; ++j) {
            int k = kq * 8 + j;
            float val = 0.f;
            if (k < 6) {
                val = (g == 0) ? Gtab[k * 768 + col]              // pre-scaled in K1
                    : (g == 1) ? Gtab[k * 768 + 256 + col]        // pre-scaled in K1
                    : (g == 2) ? b_hh[512 + col] * TWO_LOG2E_F
                               : Gtab[k * 768 + 512 + col];       // pre-scaled in K1
            }
            v[j] = (__bf16)val;
        }
    }
    *(bf16x8*)(Wg + (size_t)u * 8) = v;
}

// ---------------- K3: main recurrent kernel ----------------
__global__ __launch_bounds__(1024) void k_main(
    const float* __restrict__ latent, const int* __restrict__ tgt,
    const __bf16* __restrict__ Wg, const float* __restrict__ Wout,
    const float* __restrict__ bout, float* __restrict__ out) {

    __shared__ __bf16 h_lds[2][4][8][64][8];    // [buf][nt][kc][lane][j] : 64 KB
    __shared__ __bf16 onehot_lds[8][4][64][8];  // per-step one-hot B-frags : 32 KB
    __shared__ __bf16 woutf_lds[8][64][8];      // W_out A-frags (rows 5..15 = 0) : 8 KB
    __shared__ float  logit_lds[64 * 40];       // logits (10 KB)

    const int tid  = threadIdx.x;
    const int lane = tid & 63;
    const int w    = tid >> 6;       // wave 0..15 : gate-col slice [16w,16w+16)
    const int q    = lane >> 4;      // k-quad within frag / row-quad in C
    const int n16  = lane & 15;      // batch index within 16-row N-tile
    const int row0 = blockIdx.x * 64;

    // per-thread A-frag base; local frag f at wbase + f*512 elements
    const __bf16* wbase = Wg + ((size_t)(w * 28) * 64 + lane) * 8;

    // combine-element <-> B-frag LDS mapping:
    // element (nt, col=16w+4q+i): kc_h=w>>1, lane'=n16+16*((2w+(q>>1))&3), j=4*(q&1)+i
    const int kc_h  = w >> 1;
    const int slotl = n16 + 16 * ((2 * w + (q >> 1)) & 3);
    const int joff  = 4 * (q & 1);

    // ---- stage W_out A-frags (16 rows, 5 used) ----
    if (tid < 512) {
        int kc = tid >> 6, ln = tid & 63, m = ln & 15, kq2 = ln >> 4;
        bf16x8 v;
#pragma unroll
        for (int j = 0; j < 8; ++j)
            v[j] = (m < 5) ? (__bf16)Wout[m * 256 + kc * 32 + kq2 * 8 + j] : (__bf16)0.f;
        *(bf16x8*)&woutf_lds[kc][ln][0] = v;
    }
    // ---- one-hot B-frags for all 8 steps ----
    for (int s = tid; s < 2048; s += 1024) {
        int t = s >> 8, nt = (s >> 6) & 3, ln = s & 63;
        int nn = ln & 15, kq2 = ln >> 4;
        int tok = (t == 0) ? 5 : tgt[(size_t)(row0 + nt * 16 + nn) * 8 + t - 1];
        bf16x8 v;
#pragma unroll
        for (int j = 0; j < 8; ++j) v[j] = (__bf16)((kq2 * 8 + j == tok) ? 1.f : 0.f);
        *(bf16x8*)&onehot_lds[t][nt][ln][0] = v;
    }
    // ---- init h in LDS buf 0 (bf16) ----
#pragma unroll
    for (int nt = 0; nt < 4; ++nt) {
        float4 hv = *(const float4*)(latent + (size_t)(row0 + nt * 16 + n16) * 256 + 16 * w + 4 * q);
        bf16x4 hb;
        hb[0] = (__bf16)hv.x; hb[1] = (__bf16)hv.y;
        hb[2] = (__bf16)hv.z; hb[3] = (__bf16)hv.w;
        *(bf16x4*)&h_lds[0][nt][kc_h][slotl][joff] = hb;
    }
    // logit-wave assignment: one per SIMD (waves 0,5,10,15 -> nt 0..3)
    const int lw = (w == 0) ? 0 : (w == 5) ? 1 : (w == 10) ? 2 : (w == 15) ? 3 : -1;
    const float bo0 = bout[0], bo1 = bout[1], bo2 = bout[2], bo3 = bout[3], bo4 = bout[4];
    const f32x4 z4 = {0.f, 0.f, 0.f, 0.f};
    __syncthreads();

    for (int t = 0; t < 8; ++t) {
        const int cur = t & 1, nxt = cur ^ 1;
        f32x4 acc[4][4];   // [gate][nt]; initialized by the one-hot MFMAs (C=z4)

        __builtin_amdgcn_s_setprio(1);
        // ---- one-hot K-block FIRST (C=z4 -> no acc-init movs): delivers
        //      i_r,i_z into acc0/1, bhn into acc2, i_n into acc3 ----
        {
            bf16x8 a0 = *(const bf16x8*)(wbase + (size_t)24 * 512);
            bf16x8 a1 = *(const bf16x8*)(wbase + (size_t)25 * 512);
            bf16x8 a2 = *(const bf16x8*)(wbase + (size_t)26 * 512);
            bf16x8 a3 = *(const bf16x8*)(wbase + (size_t)27 * 512);
#pragma unroll
            for (int nt = 0; nt < 4; ++nt) {
                bf16x8 oh = *(const bf16x8*)&onehot_lds[t][nt][lane][0];
                acc[0][nt] = __builtin_amdgcn_mfma_f32_16x16x32_bf16(a0, oh, z4, 0, 0, 0);
                acc[1][nt] = __builtin_amdgcn_mfma_f32_16x16x32_bf16(a1, oh, z4, 0, 0, 0);
                acc[2][nt] = __builtin_amdgcn_mfma_f32_16x16x32_bf16(a2, oh, z4, 0, 0, 0);
                acc[3][nt] = __builtin_amdgcn_mfma_f32_16x16x32_bf16(a3, oh, z4, 0, 0, 0);
            }
        }
        // ---- stream kc 0..7 from L2 (each frag loaded by exactly one wave) ----
#pragma unroll 2
        for (int kc = 0; kc < 8; ++kc) {
            bf16x8 a0 = *(const bf16x8*)(wbase + (size_t)kc * 512);
            bf16x8 a1 = *(const bf16x8*)(wbase + (size_t)(8 + kc) * 512);
            bf16x8 a2 = *(const bf16x8*)(wbase + (size_t)(16 + kc) * 512);
#pragma unroll
            for (int nt = 0; nt < 4; ++nt) {
                bf16x8 bb = *(const bf16x8*)&h_lds[cur][nt][kc][lane][0];
                acc[0][nt] = __builtin_amdgcn_mfma_f32_16x16x32_bf16(a0, bb, acc[0][nt], 0, 0, 0);
                acc[1][nt] = __builtin_amdgcn_mfma_f32_16x16x32_bf16(a1, bb, acc[1][nt], 0, 0, 0);
                acc[2][nt] = __builtin_amdgcn_mfma_f32_16x16x32_bf16(a2, bb, acc[2][nt], 0, 0, 0);
            }
        }

        // ---- logit MFMA (skewed one step), one wave per SIMD ----
        if (lw >= 0 && t > 0) {
            f32x4 lacc = z4;
#pragma unroll
            for (int kc = 0; kc < 8; ++kc) {
                bf16x8 wf = *(const bf16x8*)&woutf_lds[kc][lane][0];
                bf16x8 bb = *(const bf16x8*)&h_lds[cur][lw][kc][lane][0];
                lacc = __builtin_amdgcn_mfma_f32_16x16x32_bf16(wf, bb, lacc, 0, 0, 0);
            }
            // C: batch = lane&15, o = q*4 + i
            float* dst = &logit_lds[(lw * 16 + n16) * 40 + (t - 1) * 5];
            if (q == 0) {
                dst[0] = lacc[0] + bo0; dst[1] = lacc[1] + bo1;
                dst[2] = lacc[2] + bo2; dst[3] = lacc[3] + bo3;
            } else if (q == 1) {
                dst[4] = lacc[0] + bo4;
            }
        }
        __builtin_amdgcn_s_setprio(0);

        // ---- combine: GRU update, exp2-form (no muls), hold from LDS ----
#pragma unroll
        for (int nt = 0; nt < 4; ++nt) {
            bf16x4 hold = *(const bf16x4*)&h_lds[cur][nt][kc_h][slotl][joff];
            bf16x4 hb;
#pragma unroll
            for (int i = 0; i < 4; ++i) {
                float rg = sigm2(acc[0][nt][i]);
                float zg = sigm2(acc[1][nt][i]);
                float ng = tanh2(__builtin_fmaf(rg, acc[2][nt][i], acc[3][nt][i]));
                float hv = ng + zg * ((float)hold[i] - ng);
                hb[i] = (__bf16)hv;
            }
            *(bf16x4*)&h_lds[nxt][nt][kc_h][slotl][joff] = hb;
        }
        lds_barrier();   // h_lds[nxt] published; one barrier per step
    }

    // ---- epilogue: logits for step 7 from final h (buf 0 after t=7) ----
    if (lw >= 0) {
        f32x4 lacc = z4;
#pragma unroll
        for (int kc = 0; kc < 8; ++kc) {
            bf16x8 wf = *(const bf16x8*)&woutf_lds[kc][lane][0];
            bf16x8 bb = *(const bf16x8*)&h_lds[0][lw][kc][lane][0];
            lacc = __builtin_amdgcn_mfma_f32_16x16x32_bf16(wf, bb, lacc, 0, 0, 0);
        }
        float* dst = &logit_lds[(lw * 16 + n16) * 40 + 7 * 5];
        if (q == 0) {
            dst[0] = lacc[0] + bo0; dst[1] = lacc[1] + bo1;
            dst[2] = lacc[2] + bo2; dst[3] = lacc[3] + bo3;
        } else if (q == 1) {
            dst[4] = lacc[0] + bo4;
        }
    }
    __syncthreads();
    // ---- coalesced output dump: 64 rows x (8 t x 5 o) contiguous ----
    for (int i = tid; i < 64 * 40; i += 1024)
        out[(size_t)row0 * 40 + i] = logit_lds[i];
}

extern "C" void kernel_launch(void* const* d_in, const int* in_sizes, int n_in,
                              void* d_out, int out_size, void* d_ws, size_t ws_size,
                              hipStream_t stream) {
    const float* latent = (const float*)d_in[0];
    const int*   tgt    = (const int*)d_in[1];
    const float* emb    = (const float*)d_in[2];
    const float* W_ih   = (const float*)d_in[3];
    const float* W_hh   = (const float*)d_in[4];
    const float* b_ih   = (const float*)d_in[5];
    const float* b_hh   = (const float*)d_in[6];
    const float* W_out  = (const float*)d_in[7];
    const float* b_out  = (const float*)d_in[8];
    float* out = (float*)d_out;

    float*  Gtab = (float*)d_ws;                       // 6*768*4 = 18432 B
    __bf16* Wg   = (__bf16*)((char*)d_ws + 18432);     // 448 frags*512*2 = 458752 B

    k_gtable<<<6, 768, 0, stream>>>(emb, W_ih, b_ih, b_hh, Gtab);
    k_wfrag3<<<112, 256, 0, stream>>>(W_hh, Gtab, b_hh, Wg);
    k_main<<<1024, 1024, 0, stream>>>(latent, tgt, Wg, W_out, b_out, out);
}